// Round 1
// baseline (297.706 us; speedup 1.0000x reference)
//
#include <hip/hip_runtime.h>

#define HW     16384
#define CIN    512
#define KCH    256
#define NKEY   19
#define NKP    32
#define NBATCH 8

typedef __attribute__((ext_vector_type(8))) short s16x8;
typedef __attribute__((ext_vector_type(4))) short s16x4;
typedef __attribute__((ext_vector_type(4))) float f32x4;

__device__ __forceinline__ short f2bf(float f) {
  union { float f; unsigned u; } x;
  x.f = f;
  unsigned r = x.u + 0x7fffu + ((x.u >> 16) & 1u);
  return (short)(r >> 16);
}

// ---------------- prep 1: fold BN scales into W_p1/W_p2 (bf16), compute biases ----------
__global__ void k_fold(const float* __restrict__ w_p1, const float* __restrict__ w_p2,
                       const float* __restrict__ p1g, const float* __restrict__ p1b,
                       const float* __restrict__ p1m, const float* __restrict__ p1v,
                       const float* __restrict__ p2g, const float* __restrict__ p2b,
                       const float* __restrict__ p2m, const float* __restrict__ p2v,
                       const float* __restrict__ ug,  const float* __restrict__ ub,
                       const float* __restrict__ um,  const float* __restrict__ uvv,
                       short* __restrict__ W1, short* __restrict__ W2,
                       float* __restrict__ b1, float* __restrict__ b2, float* __restrict__ bu)
{
  int t = blockIdx.x * 256 + threadIdx.x;
  if (t < 131072) {                       // W1: [256][512]
    int o = t >> 9;
    float inv = p1g[o] * rsqrtf(p1v[o] + 1e-5f);
    W1[t] = f2bf(inv * w_p1[t]);
  } else if (t < 196608) {                // W2: [256][256]
    int u = t - 131072; int o = u >> 8;
    float inv = p2g[o] * rsqrtf(p2v[o] + 1e-5f);
    W2[u] = f2bf(inv * w_p2[u]);
  } else if (t < 196608 + 256) {
    int o = t - 196608;
    float inv = p1g[o] * rsqrtf(p1v[o] + 1e-5f);
    b1[o] = p1b[o] - p1m[o] * inv;
  } else if (t < 196608 + 512) {
    int o = t - 196608 - 256;
    float inv = p2g[o] * rsqrtf(p2v[o] + 1e-5f);
    b2[o] = p2b[o] - p2m[o] * inv;
  } else if (t < 196608 + 1024) {
    int o = t - 196608 - 512;
    float inv = ug[o] * rsqrtf(uvv[o] + 1e-5f);
    bu[o] = ub[o] - um[o] * inv;
  }
}

// ---------------- prep 2: proxy stage-1 (f_object layer1 and f_down) ----------
__global__ void k_proxy1(const float* __restrict__ proxy,
                         const float* __restrict__ w_o1, const float* __restrict__ w_d,
                         const float* __restrict__ o1g, const float* __restrict__ o1b,
                         const float* __restrict__ o1m, const float* __restrict__ o1v,
                         const float* __restrict__ dg,  const float* __restrict__ db,
                         const float* __restrict__ dm,  const float* __restrict__ dv,
                         float* __restrict__ t_o1, float* __restrict__ vmat)
{
  int t = blockIdx.x * 256 + threadIdx.x;
  const int TOT = NBATCH * KCH * NKEY;   // 38912
  if (t >= 2 * TOT) return;
  int sel = t / TOT;
  int u = t - sel * TOT;
  int n = u / (KCH * NKEY);
  int rem = u - n * (KCH * NKEY);
  int o = rem / NKEY;
  int k = rem - o * NKEY;
  const float* w  = sel ? w_d : w_o1;
  const float* gg = sel ? dg : o1g;
  const float* bb = sel ? db : o1b;
  const float* mm = sel ? dm : o1m;
  const float* vv = sel ? dv : o1v;
  const float* pr = proxy + (size_t)n * CIN * NKEY + k;
  const float* wr = w + (size_t)o * CIN;
  float acc = 0.f;
  for (int c = 0; c < CIN; ++c) acc += wr[c] * pr[(size_t)c * NKEY];
  float inv = gg[o] * rsqrtf(vv[o] + 1e-5f);
  float r = fmaxf(inv * acc + (bb[o] - mm[o] * inv), 0.f);
  (sel ? vmat : t_o1)[u] = r;
}

// ---------------- prep 3: Kmat (scaled, padded) and Wuv = inv_u * W_u @ V ----------
__global__ void k_proxy2(const float* __restrict__ w_o2, const float* __restrict__ w_u,
                         const float* __restrict__ o2g, const float* __restrict__ o2b,
                         const float* __restrict__ o2m, const float* __restrict__ o2v,
                         const float* __restrict__ ug,  const float* __restrict__ uvv,
                         const float* __restrict__ t_o1, const float* __restrict__ vmat,
                         short* __restrict__ Km, short* __restrict__ Wu)
{
  int t = blockIdx.x * 256 + threadIdx.x;
  const int TK = NBATCH * NKP * KCH;     // 65536, Km layout [n][kk][o2]
  if (t < TK) {
    int n = t / (NKP * KCH);
    int rem = t - n * (NKP * KCH);
    int kk = rem / KCH;
    int o2 = rem - kk * KCH;
    float val = 0.f;
    if (kk < NKEY) {
      const float* tp = t_o1 + (size_t)n * KCH * NKEY + kk;
      const float* wr = w_o2 + (size_t)o2 * KCH;
      float acc = 0.f;
      for (int o = 0; o < KCH; ++o) acc += wr[o] * tp[(size_t)o * NKEY];
      float inv = o2g[o2] * rsqrtf(o2v[o2] + 1e-5f);
      val = fmaxf(inv * acc + (o2b[o2] - o2m[o2] * inv), 0.f) * 0.0625f; // fold KC^-0.5
    }
    Km[t] = f2bf(val);
  } else {
    int u = t - TK;                      // Wu layout [n][c][kk], 131072
    if (u >= NBATCH * CIN * NKP) return;
    int n = u / (CIN * NKP);
    int rem = u - n * (CIN * NKP);
    int c = rem / NKP;
    int kk = rem - c * NKP;
    float val = 0.f;
    if (kk < NKEY) {
      const float* vp = vmat + (size_t)n * KCH * NKEY + kk;
      const float* wr = w_u + (size_t)c * KCH;
      float acc = 0.f;
      for (int o = 0; o < KCH; ++o) acc += wr[o] * vp[(size_t)o * NKEY];
      val = ug[c] * rsqrtf(uvv[c] + 1e-5f) * acc;
    }
    Wu[u] = f2bf(val);
  }
}

// ---------------- fused main kernel: per-wg 128-pixel tile through the whole block ----
__global__ __launch_bounds__(512) void k_main(
    const float* __restrict__ x,
    const short* __restrict__ W1, const short* __restrict__ W2,
    const short* __restrict__ Km, const short* __restrict__ Wu,
    const float* __restrict__ b1, const float* __restrict__ b2,
    const float* __restrict__ bu,
    float* __restrict__ out)
{
  // LDS: t1q [128p][256c] bf16 swizzled (64KB); xsm [128p][64c] bf16 swizzled (16KB),
  // reused late as P [128p][32k] bf16 swizzled.
  __shared__ char smem[81920];
  char* t1q = smem;
  char* xsm = smem + 65536;

  const int tid  = threadIdx.x;
  const int w    = tid >> 6;
  const int lane = tid & 63;
  const int g    = lane >> 4;
  const int i    = lane & 15;
  const int wm   = w >> 1;        // m-block (64 output channels)
  const int wn   = w & 1;         // n-block (64 pixels)
  const int n    = blockIdx.x >> 7;
  const int l0   = (blockIdx.x & 127) << 7;

  f32x4 acc[4][4];
#pragma unroll
  for (int a_ = 0; a_ < 4; ++a_)
#pragma unroll
    for (int b_ = 0; b_ < 4; ++b_) acc[a_][b_] = (f32x4)0.f;

  // ---------------- Stage A: t1 = relu(W1' @ x + b1), M=256 N=128 K=512 ----------------
  const int sp  = ((w & 1) << 6) | lane;    // staging pixel 0..127
  const int scb = (w >> 1) << 4;            // staging channel base in chunk
  const int ssw = (sp & 7) << 4;
  const float* xb = x + (size_t)n * CIN * HW + l0 + sp;

#pragma unroll 1
  for (int ck = 0; ck < 8; ++ck) {
    __syncthreads();
    // transpose-stage 64 channels x 128 pixels: coalesced strided dword loads
    float vv[16];
    const float* xp = xb + (size_t)(ck * 64 + scb) * HW;
#pragma unroll
    for (int ii = 0; ii < 16; ++ii) vv[ii] = xp[(size_t)ii * HW];
    s16x8 h0, h1;
#pragma unroll
    for (int ii = 0; ii < 8; ++ii) { h0[ii] = f2bf(vv[ii]); h1[ii] = f2bf(vv[ii + 8]); }
    char* wr = xsm + sp * 128;
    *(s16x8*)(wr + (((scb << 1) +  0) ^ ssw)) = h0;
    *(s16x8*)(wr + (((scb << 1) + 16) ^ ssw)) = h1;
    __syncthreads();

#pragma unroll
    for (int ks = 0; ks < 2; ++ks) {
      s16x8 af[4], bf[4];
#pragma unroll
      for (int mi = 0; mi < 4; ++mi)
        af[mi] = *(const s16x8*)(W1 + ((size_t)(wm * 64 + mi * 16 + i) * CIN + ck * 64 + ks * 32 + g * 8));
#pragma unroll
      for (int ni = 0; ni < 4; ++ni) {
        int p = wn * 64 + ni * 16 + i;
        bf[ni] = *(const s16x8*)(xsm + p * 128 + (((ks * 32 + g * 8) << 1) ^ ((p & 7) << 4)));
      }
#pragma unroll
      for (int mi = 0; mi < 4; ++mi)
#pragma unroll
        for (int ni = 0; ni < 4; ++ni)
          acc[mi][ni] = __builtin_amdgcn_mfma_f32_16x16x32_bf16(af[mi], bf[ni], acc[mi][ni], 0, 0, 0);
    }
  }

  // epilogue A -> t1q
#pragma unroll
  for (int mi = 0; mi < 4; ++mi) {
    f32x4 bias = *(const f32x4*)(b1 + wm * 64 + mi * 16 + g * 4);
#pragma unroll
    for (int ni = 0; ni < 4; ++ni) {
      int p = wn * 64 + ni * 16 + i;
      s16x4 hh;
#pragma unroll
      for (int r = 0; r < 4; ++r) hh[r] = f2bf(fmaxf(acc[mi][ni][r] + bias[r], 0.f));
      *(s16x4*)(t1q + p * 512 + (((wm * 64 + mi * 16 + g * 4) << 1) ^ ((p & 7) << 4))) = hh;
      acc[mi][ni] = (f32x4)0.f;
    }
  }
  __syncthreads();

  // ---------------- Stage B: q = relu(W2' @ t1 + b2), M=256 N=128 K=256 ----------------
#pragma unroll 1
  for (int ks = 0; ks < 8; ++ks) {
    s16x8 af[4], bf[4];
#pragma unroll
    for (int mi = 0; mi < 4; ++mi)
      af[mi] = *(const s16x8*)(W2 + ((size_t)(wm * 64 + mi * 16 + i) * KCH + ks * 32 + g * 8));
#pragma unroll
    for (int ni = 0; ni < 4; ++ni) {
      int p = wn * 64 + ni * 16 + i;
      bf[ni] = *(const s16x8*)(t1q + p * 512 + (((ks * 32 + g * 8) << 1) ^ ((p & 7) << 4)));
    }
#pragma unroll
    for (int mi = 0; mi < 4; ++mi)
#pragma unroll
      for (int ni = 0; ni < 4; ++ni)
        acc[mi][ni] = __builtin_amdgcn_mfma_f32_16x16x32_bf16(af[mi], bf[ni], acc[mi][ni], 0, 0, 0);
  }
  __syncthreads();              // all t1 reads complete before overwrite
#pragma unroll
  for (int mi = 0; mi < 4; ++mi) {
    f32x4 bias = *(const f32x4*)(b2 + wm * 64 + mi * 16 + g * 4);
#pragma unroll
    for (int ni = 0; ni < 4; ++ni) {
      int p = wn * 64 + ni * 16 + i;
      s16x4 hh;
#pragma unroll
      for (int r = 0; r < 4; ++r) hh[r] = f2bf(fmaxf(acc[mi][ni][r] + bias[r], 0.f));
      *(s16x4*)(t1q + p * 512 + (((wm * 64 + mi * 16 + g * 4) << 1) ^ ((p & 7) << 4))) = hh;
    }
  }
  __syncthreads();

  // ---------------- Stage S: simT = (K/16)^T-form @ q, softmax over k<19 --------------
  f32x4 as_[2];
  as_[0] = (f32x4)0.f; as_[1] = (f32x4)0.f;
  const short* Kn = Km + (size_t)n * NKP * KCH;
  const int ps = (w << 4) | i;          // this lane's pixel
  const int psw = (ps & 7) << 4;
#pragma unroll
  for (int ks = 0; ks < 8; ++ks) {
    s16x8 bq = *(const s16x8*)(t1q + ps * 512 + (((ks * 32 + g * 8) << 1) ^ psw));
#pragma unroll
    for (int mi = 0; mi < 2; ++mi) {
      s16x8 ak = *(const s16x8*)(Kn + (size_t)(mi * 16 + i) * KCH + ks * 32 + g * 8);
      as_[mi] = __builtin_amdgcn_mfma_f32_16x16x32_bf16(ak, bq, as_[mi], 0, 0, 0);
    }
  }
  float mx = -1e30f;
#pragma unroll
  for (int mi = 0; mi < 2; ++mi)
#pragma unroll
    for (int r = 0; r < 4; ++r) {
      int k = mi * 16 + g * 4 + r;
      if (k < NKEY) mx = fmaxf(mx, as_[mi][r]);
    }
  mx = fmaxf(mx, __shfl_xor(mx, 16, 64));
  mx = fmaxf(mx, __shfl_xor(mx, 32, 64));
  float e[2][4];
  float sum = 0.f;
#pragma unroll
  for (int mi = 0; mi < 2; ++mi)
#pragma unroll
    for (int r = 0; r < 4; ++r) {
      int k = mi * 16 + g * 4 + r;
      float t = (k < NKEY) ? __expf(as_[mi][r] - mx) : 0.f;
      e[mi][r] = t;
      sum += t;
    }
  sum += __shfl_xor(sum, 16, 64);
  sum += __shfl_xor(sum, 32, 64);
  float rs = 1.f / sum;
  char* P = xsm;                        // reuse xs region: [128p][32k] bf16, swizzle (p&3)<<4
#pragma unroll
  for (int mi = 0; mi < 2; ++mi) {
    s16x4 hh;
#pragma unroll
    for (int r = 0; r < 4; ++r) hh[r] = f2bf(e[mi][r] * rs);
    *(s16x4*)(P + ps * 64 + (((mi * 16 + g * 4) << 1) ^ ((ps & 3) << 4))) = hh;
  }
  __syncthreads();

  // ---------------- Stage O: out = relu(Wuv @ P + bu), M=512 N=128 K=32 ----------------
  s16x8 bP[8];
#pragma unroll
  for (int ni = 0; ni < 8; ++ni) {
    int p = ni * 16 + i;
    bP[ni] = *(const s16x8*)(P + p * 64 + ((g * 16) ^ ((p & 3) << 4)));
  }
  const short* Wn = Wu + (size_t)n * CIN * NKP;
  float* op = out + (size_t)n * CIN * HW + l0;
#pragma unroll
  for (int mi = 0; mi < 4; ++mi) {
    int row0 = w * 64 + mi * 16;
    s16x8 aU = *(const s16x8*)(Wn + (size_t)(row0 + i) * NKP + g * 8);
    f32x4 bias = *(const f32x4*)(bu + row0 + g * 4);
#pragma unroll
    for (int ni = 0; ni < 8; ++ni) {
      f32x4 o4 = __builtin_amdgcn_mfma_f32_16x16x32_bf16(aU, bP[ni], bias, 0, 0, 0);
#pragma unroll
      for (int r = 0; r < 4; ++r)
        op[(size_t)(row0 + g * 4 + r) * HW + ni * 16 + i] = fmaxf(o4[r], 0.f);
    }
  }
}

extern "C" void kernel_launch(void* const* d_in, const int* in_sizes, int n_in,
                              void* d_out, int out_size, void* d_ws, size_t ws_size,
                              hipStream_t stream) {
  (void)in_sizes; (void)n_in; (void)out_size; (void)ws_size;
  const float* x     = (const float*)d_in[0];
  const float* proxy = (const float*)d_in[1];
  const float* w_p1  = (const float*)d_in[2];
  const float* w_p2  = (const float*)d_in[3];
  const float* w_o1  = (const float*)d_in[4];
  const float* w_o2  = (const float*)d_in[5];
  const float* w_d   = (const float*)d_in[6];
  const float* w_u   = (const float*)d_in[7];
  const float* p1g = (const float*)d_in[8],  *p1b = (const float*)d_in[9];
  const float* p1m = (const float*)d_in[10], *p1v = (const float*)d_in[11];
  const float* p2g = (const float*)d_in[12], *p2b = (const float*)d_in[13];
  const float* p2m = (const float*)d_in[14], *p2v = (const float*)d_in[15];
  const float* o1g = (const float*)d_in[16], *o1b = (const float*)d_in[17];
  const float* o1m = (const float*)d_in[18], *o1v = (const float*)d_in[19];
  const float* o2g = (const float*)d_in[20], *o2b = (const float*)d_in[21];
  const float* o2m = (const float*)d_in[22], *o2v = (const float*)d_in[23];
  const float* dg  = (const float*)d_in[24], *db  = (const float*)d_in[25];
  const float* dm  = (const float*)d_in[26], *dv  = (const float*)d_in[27];
  const float* ug  = (const float*)d_in[28], *ub  = (const float*)d_in[29];
  const float* um  = (const float*)d_in[30], *uv  = (const float*)d_in[31];

  char* ws = (char*)d_ws;
  short* W1   = (short*)(ws + 0);        // 262144 B
  short* W2   = (short*)(ws + 262144);   // 131072 B
  short* Km   = (short*)(ws + 393216);   // 131072 B  [8][32][256] bf16
  short* Wu   = (short*)(ws + 524288);   // 262144 B  [8][512][32] bf16
  float* b1   = (float*)(ws + 786432);   // 1024 B
  float* b2   = (float*)(ws + 787456);   // 1024 B
  float* bu   = (float*)(ws + 788480);   // 2048 B
  float* t_o1 = (float*)(ws + 790528);   // 622592 B  [8][256][19] f32
  float* vmat = (float*)(ws + 1413120);  // 622592 B

  k_fold<<<772, 256, 0, stream>>>(w_p1, w_p2, p1g, p1b, p1m, p1v,
                                  p2g, p2b, p2m, p2v, ug, ub, um, uv,
                                  W1, W2, b1, b2, bu);
  k_proxy1<<<304, 256, 0, stream>>>(proxy, w_o1, w_d,
                                    o1g, o1b, o1m, o1v, dg, db, dm, dv,
                                    t_o1, vmat);
  k_proxy2<<<768, 256, 0, stream>>>(w_o2, w_u, o2g, o2b, o2m, o2v, ug, uv,
                                    t_o1, vmat, Km, Wu);
  k_main<<<1024, 512, 0, stream>>>(x, W1, W2, Km, Wu, b1, b2, bu, (float*)d_out);
}

// Round 2
// 237.931 us; speedup vs baseline: 1.2512x; 1.2512x over previous
//
#include <hip/hip_runtime.h>

#define HW     16384
#define CIN    512
#define KCH    256
#define NKEY   19
#define NKP    32
#define NBATCH 8

typedef __attribute__((ext_vector_type(8))) short s16x8;
typedef __attribute__((ext_vector_type(4))) short s16x4;
typedef __attribute__((ext_vector_type(4))) float f32x4;

__device__ __forceinline__ short f2bf(float f) {
  union { float f; unsigned u; } x;
  x.f = f;
  unsigned r = x.u + 0x7fffu + ((x.u >> 16) & 1u);
  return (short)(r >> 16);
}

// ---------------- prep 1 (merged): fold BN into W1/W2 + biases, AND proxy stage-1 -----
__global__ void k_prep1(const float* __restrict__ w_p1, const float* __restrict__ w_p2,
                        const float* __restrict__ p1g, const float* __restrict__ p1b,
                        const float* __restrict__ p1m, const float* __restrict__ p1v,
                        const float* __restrict__ p2g, const float* __restrict__ p2b,
                        const float* __restrict__ p2m, const float* __restrict__ p2v,
                        const float* __restrict__ ug,  const float* __restrict__ ub,
                        const float* __restrict__ um,  const float* __restrict__ uvv,
                        short* __restrict__ W1, short* __restrict__ W2,
                        float* __restrict__ b1, float* __restrict__ b2, float* __restrict__ bu,
                        const float* __restrict__ proxy,
                        const float* __restrict__ w_o1, const float* __restrict__ w_d,
                        const float* __restrict__ o1g, const float* __restrict__ o1b,
                        const float* __restrict__ o1m, const float* __restrict__ o1v,
                        const float* __restrict__ dg,  const float* __restrict__ db,
                        const float* __restrict__ dm,  const float* __restrict__ dv,
                        float* __restrict__ t_o1, float* __restrict__ vmat)
{
  if (blockIdx.x < 772) {
    int t = blockIdx.x * 256 + threadIdx.x;
    if (t < 131072) {                       // W1: [256][512]
      int o = t >> 9;
      float inv = p1g[o] * rsqrtf(p1v[o] + 1e-5f);
      W1[t] = f2bf(inv * w_p1[t]);
    } else if (t < 196608) {                // W2: [256][256]
      int u = t - 131072; int o = u >> 8;
      float inv = p2g[o] * rsqrtf(p2v[o] + 1e-5f);
      W2[u] = f2bf(inv * w_p2[u]);
    } else if (t < 196608 + 256) {
      int o = t - 196608;
      float inv = p1g[o] * rsqrtf(p1v[o] + 1e-5f);
      b1[o] = p1b[o] - p1m[o] * inv;
    } else if (t < 196608 + 512) {
      int o = t - 196608 - 256;
      float inv = p2g[o] * rsqrtf(p2v[o] + 1e-5f);
      b2[o] = p2b[o] - p2m[o] * inv;
    } else if (t < 196608 + 1024) {
      int o = t - 196608 - 512;
      float inv = ug[o] * rsqrtf(uvv[o] + 1e-5f);
      bu[o] = ub[o] - um[o] * inv;
    }
    return;
  }
  int t = (blockIdx.x - 772) * 256 + threadIdx.x;
  const int TOT = NBATCH * KCH * NKEY;   // 38912
  if (t >= 2 * TOT) return;
  int sel = t / TOT;
  int u = t - sel * TOT;
  int n = u / (KCH * NKEY);
  int rem = u - n * (KCH * NKEY);
  int o = rem / NKEY;
  int k = rem - o * NKEY;
  const float* w  = sel ? w_d : w_o1;
  const float* gg = sel ? dg : o1g;
  const float* bb = sel ? db : o1b;
  const float* mm = sel ? dm : o1m;
  const float* vv = sel ? dv : o1v;
  const float* pr = proxy + (size_t)n * CIN * NKEY + k;
  const float* wr = w + (size_t)o * CIN;
  f32x4 a4 = (f32x4)0.f;
  for (int c4 = 0; c4 < CIN / 4; ++c4) {
    f32x4 wv = *(const f32x4*)(wr + (c4 << 2));
    int c = c4 << 2;
    a4[0] += wv[0] * pr[(size_t)(c + 0) * NKEY];
    a4[1] += wv[1] * pr[(size_t)(c + 1) * NKEY];
    a4[2] += wv[2] * pr[(size_t)(c + 2) * NKEY];
    a4[3] += wv[3] * pr[(size_t)(c + 3) * NKEY];
  }
  float acc = a4[0] + a4[1] + a4[2] + a4[3];
  float inv = gg[o] * rsqrtf(vv[o] + 1e-5f);
  float r = fmaxf(inv * acc + (bb[o] - mm[o] * inv), 0.f);
  (sel ? vmat : t_o1)[u] = r;
}

// ---------------- prep 2: Kmat (scaled, padded) and Wuv = inv_u * W_u @ V ----------
__global__ void k_proxy2(const float* __restrict__ w_o2, const float* __restrict__ w_u,
                         const float* __restrict__ o2g, const float* __restrict__ o2b,
                         const float* __restrict__ o2m, const float* __restrict__ o2v,
                         const float* __restrict__ ug,  const float* __restrict__ uvv,
                         const float* __restrict__ t_o1, const float* __restrict__ vmat,
                         short* __restrict__ Km, short* __restrict__ Wu)
{
  int t = blockIdx.x * 256 + threadIdx.x;
  const int TK = NBATCH * NKP * KCH;     // 65536, Km layout [n][kk][o2]
  if (t < TK) {
    int n = t / (NKP * KCH);
    int rem = t - n * (NKP * KCH);
    int kk = rem / KCH;
    int o2 = rem - kk * KCH;
    float val = 0.f;
    if (kk < NKEY) {
      const float* tp = t_o1 + (size_t)n * KCH * NKEY + kk;
      const float* wr = w_o2 + (size_t)o2 * KCH;
      f32x4 a4 = (f32x4)0.f;
      for (int o4 = 0; o4 < KCH / 4; ++o4) {
        f32x4 wv = *(const f32x4*)(wr + (o4 << 2));
        int o = o4 << 2;
        a4[0] += wv[0] * tp[(size_t)(o + 0) * NKEY];
        a4[1] += wv[1] * tp[(size_t)(o + 1) * NKEY];
        a4[2] += wv[2] * tp[(size_t)(o + 2) * NKEY];
        a4[3] += wv[3] * tp[(size_t)(o + 3) * NKEY];
      }
      float acc = a4[0] + a4[1] + a4[2] + a4[3];
      float inv = o2g[o2] * rsqrtf(o2v[o2] + 1e-5f);
      val = fmaxf(inv * acc + (o2b[o2] - o2m[o2] * inv), 0.f) * 0.0625f; // fold KC^-0.5
    }
    Km[t] = f2bf(val);
  } else {
    int u = t - TK;                      // Wu layout [n][c][kk], 131072
    if (u >= NBATCH * CIN * NKP) return;
    int n = u / (CIN * NKP);
    int rem = u - n * (CIN * NKP);
    int c = rem / NKP;
    int kk = rem - c * NKP;
    float val = 0.f;
    if (kk < NKEY) {
      const float* vp = vmat + (size_t)n * KCH * NKEY + kk;
      const float* wr = w_u + (size_t)c * KCH;
      f32x4 a4 = (f32x4)0.f;
      for (int o4 = 0; o4 < KCH / 4; ++o4) {
        f32x4 wv = *(const f32x4*)(wr + (o4 << 2));
        int o = o4 << 2;
        a4[0] += wv[0] * vp[(size_t)(o + 0) * NKEY];
        a4[1] += wv[1] * vp[(size_t)(o + 1) * NKEY];
        a4[2] += wv[2] * vp[(size_t)(o + 2) * NKEY];
        a4[3] += wv[3] * vp[(size_t)(o + 3) * NKEY];
      }
      float acc = a4[0] + a4[1] + a4[2] + a4[3];
      val = ug[c] * rsqrtf(uvv[c] + 1e-5f) * acc;
    }
    Wu[u] = f2bf(val);
  }
}

// ---------------- fused main kernel ----------------------------------------------------
// LDS (64 KB total, 2 wg/CU):
//   [0, 65536)  t1q  [128p][256c] bf16 swizzled  (live: stage A epilogue .. stage S)
//   [0, 16384)  xbuf0 \ stage-A staging double buffer [128p][64c] bf16 swizzled
//   [16384,32768) xbuf1/  (aliases t1q; t1q written only at stage-A epilogue)
//   [0, 8192)   P    [128p][32k] bf16 swizzled   (after stage S; t1q dead)
__global__ __launch_bounds__(512, 4) void k_main(
    const float* __restrict__ x,
    const short* __restrict__ W1, const short* __restrict__ W2,
    const short* __restrict__ Km, const short* __restrict__ Wu,
    const float* __restrict__ b1, const float* __restrict__ b2,
    const float* __restrict__ bu,
    float* __restrict__ out)
{
  __shared__ char smem[65536];
  char* t1q = smem;

  const int tid  = threadIdx.x;
  const int w    = tid >> 6;
  const int lane = tid & 63;
  const int g    = lane >> 4;
  const int i    = lane & 15;
  const int wm   = w >> 1;        // m-block (64 output channels)
  const int wn   = w & 1;         // n-block (64 pixels)
  const int n    = blockIdx.x >> 7;
  const int l0   = (blockIdx.x & 127) << 7;

  f32x4 acc[4][4];
#pragma unroll
  for (int a_ = 0; a_ < 4; ++a_)
#pragma unroll
    for (int b_ = 0; b_ < 4; ++b_) acc[a_][b_] = (f32x4)0.f;

  // ---------------- Stage A: t1 = relu(W1' @ x + b1), M=256 N=128 K=512 ----------------
  const int sp  = ((w & 1) << 6) | lane;    // staging pixel 0..127
  const int scb = (w >> 1) << 4;            // staging channel base in chunk
  const int ssw = (sp & 7) << 4;
  const float* xb = x + (size_t)n * CIN * HW + l0 + sp;

  // prologue: stage chunk 0 -> xbuf0
  {
    const float* xp = xb + (size_t)scb * HW;
    float vv[16];
#pragma unroll
    for (int ii = 0; ii < 16; ++ii) vv[ii] = xp[(size_t)ii * HW];
    s16x8 h0, h1;
#pragma unroll
    for (int ii = 0; ii < 8; ++ii) { h0[ii] = f2bf(vv[ii]); h1[ii] = f2bf(vv[ii + 8]); }
    char* wr = smem + sp * 128;
    *(s16x8*)(wr + (((scb << 1) +  0) ^ ssw)) = h0;
    *(s16x8*)(wr + (((scb << 1) + 16) ^ ssw)) = h1;
  }
  __syncthreads();

#pragma unroll 1
  for (int ck = 0; ck < 8; ++ck) {
    // issue next chunk's global loads BEFORE the MFMAs (latency hides under compute)
    float vn[16];
    if (ck < 7) {
      const float* xp = xb + (size_t)((ck + 1) * 64 + scb) * HW;
#pragma unroll
      for (int ii = 0; ii < 16; ++ii) vn[ii] = xp[(size_t)ii * HW];
    }
    const char* rb = smem + ((ck & 1) << 14);
#pragma unroll
    for (int ks = 0; ks < 2; ++ks) {
      s16x8 af[4], bf[4];
#pragma unroll
      for (int mi = 0; mi < 4; ++mi)
        af[mi] = *(const s16x8*)(W1 + ((size_t)(wm * 64 + mi * 16 + i) * CIN + ck * 64 + ks * 32 + g * 8));
#pragma unroll
      for (int ni = 0; ni < 4; ++ni) {
        int p = wn * 64 + ni * 16 + i;
        bf[ni] = *(const s16x8*)(rb + p * 128 + (((ks * 32 + g * 8) << 1) ^ ((p & 7) << 4)));
      }
#pragma unroll
      for (int mi = 0; mi < 4; ++mi)
#pragma unroll
        for (int ni = 0; ni < 4; ++ni)
          acc[mi][ni] = __builtin_amdgcn_mfma_f32_16x16x32_bf16(af[mi], bf[ni], acc[mi][ni], 0, 0, 0);
    }
    if (ck < 7) {
      s16x8 h0, h1;
#pragma unroll
      for (int ii = 0; ii < 8; ++ii) { h0[ii] = f2bf(vn[ii]); h1[ii] = f2bf(vn[ii + 8]); }
      char* wr = smem + (((ck + 1) & 1) << 14) + sp * 128;
      *(s16x8*)(wr + (((scb << 1) +  0) ^ ssw)) = h0;
      *(s16x8*)(wr + (((scb << 1) + 16) ^ ssw)) = h1;
    }
    __syncthreads();
  }

  // epilogue A -> t1q (overwrites staging region; all reads drained at loop's last barrier)
#pragma unroll
  for (int mi = 0; mi < 4; ++mi) {
    f32x4 bias = *(const f32x4*)(b1 + wm * 64 + mi * 16 + g * 4);
#pragma unroll
    for (int ni = 0; ni < 4; ++ni) {
      int p = wn * 64 + ni * 16 + i;
      s16x4 hh;
#pragma unroll
      for (int r = 0; r < 4; ++r) hh[r] = f2bf(fmaxf(acc[mi][ni][r] + bias[r], 0.f));
      *(s16x4*)(t1q + p * 512 + (((wm * 64 + mi * 16 + g * 4) << 1) ^ ((p & 7) << 4))) = hh;
      acc[mi][ni] = (f32x4)0.f;
    }
  }
  __syncthreads();

  // ---------------- Stage B: q = relu(W2' @ t1 + b2), M=256 N=128 K=256 ----------------
#pragma unroll 1
  for (int ks = 0; ks < 8; ++ks) {
    s16x8 af[4], bf[4];
#pragma unroll
    for (int mi = 0; mi < 4; ++mi)
      af[mi] = *(const s16x8*)(W2 + ((size_t)(wm * 64 + mi * 16 + i) * KCH + ks * 32 + g * 8));
#pragma unroll
    for (int ni = 0; ni < 4; ++ni) {
      int p = wn * 64 + ni * 16 + i;
      bf[ni] = *(const s16x8*)(t1q + p * 512 + (((ks * 32 + g * 8) << 1) ^ ((p & 7) << 4)));
    }
#pragma unroll
    for (int mi = 0; mi < 4; ++mi)
#pragma unroll
      for (int ni = 0; ni < 4; ++ni)
        acc[mi][ni] = __builtin_amdgcn_mfma_f32_16x16x32_bf16(af[mi], bf[ni], acc[mi][ni], 0, 0, 0);
  }
  __syncthreads();              // all t1 reads complete before overwrite
#pragma unroll
  for (int mi = 0; mi < 4; ++mi) {
    f32x4 bias = *(const f32x4*)(b2 + wm * 64 + mi * 16 + g * 4);
#pragma unroll
    for (int ni = 0; ni < 4; ++ni) {
      int p = wn * 64 + ni * 16 + i;
      s16x4 hh;
#pragma unroll
      for (int r = 0; r < 4; ++r) hh[r] = f2bf(fmaxf(acc[mi][ni][r] + bias[r], 0.f));
      *(s16x4*)(t1q + p * 512 + (((wm * 64 + mi * 16 + g * 4) << 1) ^ ((p & 7) << 4))) = hh;
    }
  }
  __syncthreads();

  // ---------------- Stage S: simT = K_scaled @ q, softmax over k<19 --------------------
  f32x4 as_[2];
  as_[0] = (f32x4)0.f; as_[1] = (f32x4)0.f;
  const short* Kn = Km + (size_t)n * NKP * KCH;
  const int ps = (w << 4) | i;          // this lane's pixel
  const int psw = (ps & 7) << 4;
#pragma unroll
  for (int ks = 0; ks < 8; ++ks) {
    s16x8 bq = *(const s16x8*)(t1q + ps * 512 + (((ks * 32 + g * 8) << 1) ^ psw));
#pragma unroll
    for (int mi = 0; mi < 2; ++mi) {
      s16x8 ak = *(const s16x8*)(Kn + (size_t)(mi * 16 + i) * KCH + ks * 32 + g * 8);
      as_[mi] = __builtin_amdgcn_mfma_f32_16x16x32_bf16(ak, bq, as_[mi], 0, 0, 0);
    }
  }
  float mx = -1e30f;
#pragma unroll
  for (int mi = 0; mi < 2; ++mi)
#pragma unroll
    for (int r = 0; r < 4; ++r) {
      int k = mi * 16 + g * 4 + r;
      if (k < NKEY) mx = fmaxf(mx, as_[mi][r]);
    }
  mx = fmaxf(mx, __shfl_xor(mx, 16, 64));
  mx = fmaxf(mx, __shfl_xor(mx, 32, 64));
  float e[2][4];
  float sum = 0.f;
#pragma unroll
  for (int mi = 0; mi < 2; ++mi)
#pragma unroll
    for (int r = 0; r < 4; ++r) {
      int k = mi * 16 + g * 4 + r;
      float t = (k < NKEY) ? __expf(as_[mi][r] - mx) : 0.f;
      e[mi][r] = t;
      sum += t;
    }
  sum += __shfl_xor(sum, 16, 64);
  sum += __shfl_xor(sum, 32, 64);
  float rs = 1.f / sum;
  __syncthreads();                      // all t1q reads done before P overwrites it
  char* P = smem;                       // [128p][32k] bf16, swizzle (p&3)<<4
#pragma unroll
  for (int mi = 0; mi < 2; ++mi) {
    s16x4 hh;
#pragma unroll
    for (int r = 0; r < 4; ++r) hh[r] = f2bf(e[mi][r] * rs);
    *(s16x4*)(P + ps * 64 + (((mi * 16 + g * 4) << 1) ^ ((ps & 3) << 4))) = hh;
  }
  __syncthreads();

  // ---------------- Stage O: out = relu(Wuv @ P + bu), M=512 N=128 K=32 ----------------
  s16x8 bP[8];
#pragma unroll
  for (int ni = 0; ni < 8; ++ni) {
    int p = ni * 16 + i;
    bP[ni] = *(const s16x8*)(P + p * 64 + ((g * 16) ^ ((p & 3) << 4)));
  }
  const short* Wn = Wu + (size_t)n * CIN * NKP;
  float* op = out + (size_t)n * CIN * HW + l0;
#pragma unroll
  for (int mi = 0; mi < 4; ++mi) {
    int row0 = w * 64 + mi * 16;
    s16x8 aU = *(const s16x8*)(Wn + (size_t)(row0 + i) * NKP + g * 8);
    f32x4 bias = *(const f32x4*)(bu + row0 + g * 4);
#pragma unroll
    for (int ni = 0; ni < 8; ++ni) {
      f32x4 o4 = __builtin_amdgcn_mfma_f32_16x16x32_bf16(aU, bP[ni], bias, 0, 0, 0);
#pragma unroll
      for (int r = 0; r < 4; ++r)
        op[(size_t)(row0 + g * 4 + r) * HW + ni * 16 + i] = fmaxf(o4[r], 0.f);
    }
  }
}

extern "C" void kernel_launch(void* const* d_in, const int* in_sizes, int n_in,
                              void* d_out, int out_size, void* d_ws, size_t ws_size,
                              hipStream_t stream) {
  (void)in_sizes; (void)n_in; (void)out_size; (void)ws_size;
  const float* x     = (const float*)d_in[0];
  const float* proxy = (const float*)d_in[1];
  const float* w_p1  = (const float*)d_in[2];
  const float* w_p2  = (const float*)d_in[3];
  const float* w_o1  = (const float*)d_in[4];
  const float* w_o2  = (const float*)d_in[5];
  const float* w_d   = (const float*)d_in[6];
  const float* w_u   = (const float*)d_in[7];
  const float* p1g = (const float*)d_in[8],  *p1b = (const float*)d_in[9];
  const float* p1m = (const float*)d_in[10], *p1v = (const float*)d_in[11];
  const float* p2g = (const float*)d_in[12], *p2b = (const float*)d_in[13];
  const float* p2m = (const float*)d_in[14], *p2v = (const float*)d_in[15];
  const float* o1g = (const float*)d_in[16], *o1b = (const float*)d_in[17];
  const float* o1m = (const float*)d_in[18], *o1v = (const float*)d_in[19];
  const float* o2g = (const float*)d_in[20], *o2b = (const float*)d_in[21];
  const float* o2m = (const float*)d_in[22], *o2v = (const float*)d_in[23];
  const float* dg  = (const float*)d_in[24], *db  = (const float*)d_in[25];
  const float* dm  = (const float*)d_in[26], *dv  = (const float*)d_in[27];
  const float* ug  = (const float*)d_in[28], *ub  = (const float*)d_in[29];
  const float* um  = (const float*)d_in[30], *uv  = (const float*)d_in[31];

  char* ws = (char*)d_ws;
  short* W1   = (short*)(ws + 0);        // 262144 B
  short* W2   = (short*)(ws + 262144);   // 131072 B
  short* Km   = (short*)(ws + 393216);   // 131072 B  [8][32][256] bf16
  short* Wu   = (short*)(ws + 524288);   // 262144 B  [8][512][32] bf16
  float* b1   = (float*)(ws + 786432);   // 1024 B
  float* b2   = (float*)(ws + 787456);   // 1024 B
  float* bu   = (float*)(ws + 788480);   // 2048 B
  float* t_o1 = (float*)(ws + 790528);   // 622592 B  [8][256][19] f32
  float* vmat = (float*)(ws + 1413120);  // 622592 B

  k_prep1<<<1076, 256, 0, stream>>>(w_p1, w_p2, p1g, p1b, p1m, p1v,
                                    p2g, p2b, p2m, p2v, ug, ub, um, uv,
                                    W1, W2, b1, b2, bu,
                                    proxy, w_o1, w_d,
                                    o1g, o1b, o1m, o1v, dg, db, dm, dv,
                                    t_o1, vmat);
  k_proxy2<<<768, 256, 0, stream>>>(w_o2, w_u, o2g, o2b, o2m, o2v, ug, uv,
                                    t_o1, vmat, Km, Wu);
  k_main<<<1024, 512, 0, stream>>>(x, W1, W2, Km, Wu, b1, b2, bu, (float*)d_out);
}